// Round 2
// baseline (2620.007 us; speedup 1.0000x reference)
//
#include <hip/hip_runtime.h>
#include <cstdint>
#include <cstddef>

using bf16 = __bf16;
typedef __bf16 bf16x8 __attribute__((ext_vector_type(8)));
typedef __bf16 bf16x4 __attribute__((ext_vector_type(4)));
typedef float  f32x4  __attribute__((ext_vector_type(4)));

// ---- problem constants ----
constexpr int NB   = 2;      // batch
constexpr int NN   = 2048;   // seq
constexpr int DIM  = 1024;
constexpr int NH   = 8;
constexpr int DH   = 64;
constexpr int INNER= 512;
constexpr int FF   = 2730;
constexpr int FFP  = 2816;   // padded FF (22*128)
constexpr int MROW = NB * NN;   // 4096
constexpr int NLAY = 6;

// async global->LDS, 16B per lane; lds dest must be wave-uniform base (+lane*16 by HW)
__device__ __forceinline__ void gload_lds16(const bf16* g, bf16* l) {
  __builtin_amdgcn_global_load_lds((const __attribute__((address_space(1))) void*)g,
                                   (__attribute__((address_space(3))) void*)l,
                                   16, 0, 0);
}

// ======================= bias table ==========================
__global__ void btab_kernel(const float* __restrict__ rel, float* __restrict__ btab) {
  int d = blockIdx.x * 256 + threadIdx.x;
  if (d >= NN) return;
  int bucket;
  if (d < 16) bucket = d;
  else {
    int vl = 16 + (int)(logf((float)d / 16.0f) / logf(8.0f) * 16.0f);
    bucket = vl < 31 ? vl : 31;
  }
  for (int h = 0; h < NH; ++h) btab[h * NN + d] = rel[bucket * NH + h];
}

// ============== weight convert + transpose (+pad, +scale) ==============
__global__ void conv_tr(const float* __restrict__ src, size_t srcLayer, int srcStride,
                        int colOff, int R, int C,
                        bf16* __restrict__ dst, size_t dstLayer, int Tcols, float scale) {
  __shared__ float tile[32][33];
  const int i0 = blockIdx.x * 32, j0 = blockIdx.y * 32, z = blockIdx.z;
  const float* s = src + (size_t)z * srcLayer;
  bf16* d = dst + (size_t)z * dstLayer;
  const int tx = threadIdx.x, ty = threadIdx.y;
#pragma unroll
  for (int k = 0; k < 4; ++k) {
    int j = j0 + ty + k * 8;
    int i = i0 + tx;
    float v = 0.0f;
    if (j < R && i < C) v = s[(size_t)j * srcStride + colOff + i] * scale;
    tile[ty + k * 8][tx] = v;
  }
  __syncthreads();
#pragma unroll
  for (int k = 0; k < 4; ++k) {
    int i = i0 + ty + k * 8;   // dst row
    int j = j0 + tx;           // dst col
    d[(size_t)i * Tcols + j] = (bf16)tile[tx][ty + k * 8];
  }
}

// ======================= LayerNorm ==========================
template <typename OUT>
__global__ void ln_kernel(const float* __restrict__ X, const float* __restrict__ G,
                          const float* __restrict__ Bt, OUT* __restrict__ out) {
  __shared__ float red[8];
  const int row = blockIdx.x, t = threadIdx.x;
  const float* xr = X + (size_t)row * DIM;
  float4 v = *(const float4*)(xr + t * 4);
  float s  = v.x + v.y + v.z + v.w;
  float s2 = v.x * v.x + v.y * v.y + v.z * v.z + v.w * v.w;
#pragma unroll
  for (int o = 1; o < 64; o <<= 1) { s += __shfl_xor(s, o); s2 += __shfl_xor(s2, o); }
  if ((t & 63) == 0) { red[t >> 6] = s; red[4 + (t >> 6)] = s2; }
  __syncthreads();
  float S  = red[0] + red[1] + red[2] + red[3];
  float S2 = red[4] + red[5] + red[6] + red[7];
  const float inv = 1.0f / (float)DIM;
  float mu = S * inv;
  float var = S2 * inv - mu * mu;
  float rstd = rsqrtf(var + 1e-5f);
  float4 g  = *(const float4*)(G + t * 4);
  float4 bb = *(const float4*)(Bt + t * 4);
  OUT* orow = out + (size_t)row * DIM + t * 4;
  orow[0] = (OUT)((v.x - mu) * rstd * g.x + bb.x);
  orow[1] = (OUT)((v.y - mu) * rstd * g.y + bb.y);
  orow[2] = (OUT)((v.z - mu) * rstd * g.z + bb.z);
  orow[3] = (OUT)((v.w - mu) * rstd * g.w + bb.w);
}

// ======================= GEMM: C[M,N] = A[M,K] @ B^T[N,K] ==========================
// 128x128 tile, BK=64, 4 waves (2x2), m97 structure: global_load_lds w16 staging,
// 2 barriers per K-step. MODE 0: store bf16 C. MODE 1: Xr += acc (fp32 residual).
template <int MODE>
__launch_bounds__(256)
__global__ void gemm_bt(const bf16* __restrict__ A, const bf16* __restrict__ B,
                        int K, int N, bf16* __restrict__ Cb, float* __restrict__ Xr) {
  __shared__ __align__(16) bf16 AsF[128 * 64];
  __shared__ __align__(16) bf16 BsF[128 * 64];
  const int tid = threadIdx.x;
  const int lane = tid & 63, wave = tid >> 6;
  const int m0 = blockIdx.y * 128, n0 = blockIdx.x * 128;
  const int wm = (wave >> 1) * 64, wn = (wave & 1) * 64;
  const int fr = lane & 15, fg8 = (lane >> 4) * 8;
  const int rL = lane >> 3;          // staging row-within-8-group
  const int cL = (lane & 7) * 8;     // staging col (elements)
  const bf16* aBase = A + (size_t)(m0 + wave * 8 + rL) * K + cL;
  const bf16* bBase = B + (size_t)(n0 + wave * 8 + rL) * K + cL;
  f32x4 acc[4][4] = {};

  for (int kt = 0; kt < K; kt += 64) {
    __syncthreads();   // previous compute done reading LDS
#pragma unroll
    for (int r = 0; r < 4; ++r) {
      gload_lds16(aBase + (size_t)(r * 32) * K + kt, AsF + (r * 4 + wave) * 512);
      gload_lds16(bBase + (size_t)(r * 32) * K + kt, BsF + (r * 4 + wave) * 512);
    }
    __syncthreads();   // drains vmcnt(0): DMA complete
#pragma unroll
    for (int kk = 0; kk < 64; kk += 32) {
      bf16x8 af[4], bfr[4];
#pragma unroll
      for (int m = 0; m < 4; ++m) af[m]  = *(const bf16x8*)&AsF[(wm + m * 16 + fr) * 64 + kk + fg8];
#pragma unroll
      for (int n = 0; n < 4; ++n) bfr[n] = *(const bf16x8*)&BsF[(wn + n * 16 + fr) * 64 + kk + fg8];
#pragma unroll
      for (int m = 0; m < 4; ++m)
#pragma unroll
        for (int n = 0; n < 4; ++n)
          acc[m][n] = __builtin_amdgcn_mfma_f32_16x16x32_bf16(af[m], bfr[n], acc[m][n], 0, 0, 0);
    }
  }
  // epilogue: C layout col=lane&15, row=(lane>>4)*4+reg
  const int cc = lane & 15, cg = (lane >> 4) * 4;
#pragma unroll
  for (int m = 0; m < 4; ++m) {
#pragma unroll
    for (int n = 0; n < 4; ++n) {
      const int col = n0 + wn + n * 16 + cc;
#pragma unroll
      for (int r = 0; r < 4; ++r) {
        const int row = m0 + wm + m * 16 + cg + r;
        const size_t idx = (size_t)row * N + col;
        if (MODE == 0) Cb[idx] = (bf16)acc[m][n][r];
        else           Xr[idx] += acc[m][n][r];
      }
    }
  }
}

// ======================= V transpose: VT[b][dh][n] = KV[b*NN+n][64+dh] ==========
__global__ void vt_kernel(const bf16* __restrict__ KV, bf16* __restrict__ VT) {
  __shared__ bf16 t[32][33];
  const int n0 = blockIdx.x * 32, d0 = blockIdx.y * 32, b = blockIdx.z;
  const int tx = threadIdx.x, ty = threadIdx.y;
#pragma unroll
  for (int k = 0; k < 4; ++k) {
    int n = n0 + ty + k * 8;
    t[ty + k * 8][tx] = KV[(size_t)(b * NN + n) * 128 + 64 + d0 + tx];
  }
  __syncthreads();
#pragma unroll
  for (int k = 0; k < 4; ++k) {
    int dh = d0 + ty + k * 8;
    VT[(size_t)(b * 64 + dh) * NN + n0 + tx] = t[tx][ty + k * 8];
  }
}

// ======================= attention ==========================
// 1 wave/block, 16 q rows per (b,h). Swapped QK^T: mfma(K,Q) -> lane holds
// S[q=lane&15][kv=(lane>>4)*4+r]. Online softmax fp32. KV unrolled by 64 with
// all K/V loads issued up front (V independent of softmax). qt reversed so the
// longest causal blocks are dispatched first.
__launch_bounds__(64)
__global__ void attn_kernel(const bf16* __restrict__ Q, const bf16* __restrict__ KV,
                            const bf16* __restrict__ VT, const float* __restrict__ btab,
                            bf16* __restrict__ O) {
  __shared__ bf16 P_lds[2][16][40];
  const int lane = threadIdx.x;
  const int qt = gridDim.x - 1 - blockIdx.x;   // longest-first
  const int h = blockIdx.y, b = blockIdx.z;
  const int q0 = qt * 16;
  const int fr = lane & 15, fg = lane >> 4;
  const float* bt = btab + h * NN;
  bf16x8 qf0, qf1;
  {
    const size_t qoff = (size_t)(b * NN + q0 + fr) * INNER + h * DH + fg * 8;
    qf0 = *(const bf16x8*)(Q + qoff);
    qf1 = *(const bf16x8*)(Q + qoff + 32);
  }
  f32x4 Oacc[4] = {};
  float m_run = -1e30f, l_run = 0.0f;
  const int kv_end = q0 + 16;
  int kv0 = 0;
  // ---- main: 64 kv per iteration ----
  for (; kv0 + 64 <= kv_end; kv0 += 64) {
    bf16x8 kf[4][2];
#pragma unroll
    for (int t = 0; t < 4; ++t) {
      const size_t koff = (size_t)(b * NN + kv0 + t * 16 + fr) * 128 + fg * 8;
      kf[t][0] = *(const bf16x8*)(KV + koff);
      kf[t][1] = *(const bf16x8*)(KV + koff + 32);
    }
    bf16x8 vf[2][4];
#pragma unroll
    for (int ch = 0; ch < 2; ++ch)
#pragma unroll
      for (int c = 0; c < 4; ++c)
        vf[ch][c] = *(const bf16x8*)(VT + (size_t)(b * 64 + c * 16 + fr) * NN + kv0 + ch * 32 + fg * 8);
    f32x4 z[4];
#pragma unroll
    for (int t = 0; t < 4; ++t) {
      f32x4 zz = {0.f, 0.f, 0.f, 0.f};
      zz = __builtin_amdgcn_mfma_f32_16x16x32_bf16(kf[t][0], qf0, zz, 0, 0, 0);
      zz = __builtin_amdgcn_mfma_f32_16x16x32_bf16(kf[t][1], qf1, zz, 0, 0, 0);
      z[t] = zz;
    }
    float sv[16];
    float mx = -1e30f;
#pragma unroll
    for (int t = 0; t < 4; ++t)
#pragma unroll
      for (int r = 0; r < 4; ++r) {
        const int kv = kv0 + t * 16 + fg * 4 + r;
        const int d = (q0 + fr) - kv;
        const int dc = d > 0 ? d : 0;
        float val = z[t][r] + bt[dc];
        if (d < 0) val = -1e30f;
        sv[t * 4 + r] = val;
        mx = fmaxf(mx, val);
      }
    mx = fmaxf(mx, __shfl_xor(mx, 16));
    mx = fmaxf(mx, __shfl_xor(mx, 32));
    const float m_new = fmaxf(m_run, mx);
    const float sc_old = __expf(m_run - m_new);
    float csum = 0.0f;
#pragma unroll
    for (int i = 0; i < 16; ++i) { sv[i] = __expf(sv[i] - m_new); csum += sv[i]; }
    csum += __shfl_xor(csum, 16);
    csum += __shfl_xor(csum, 32);
    l_run = l_run * sc_old + csum;
    m_run = m_new;
#pragma unroll
    for (int r = 0; r < 4; ++r) {
      const float f = __shfl(sc_old, fg * 4 + r);
#pragma unroll
      for (int c = 0; c < 4; ++c) Oacc[c][r] *= f;
    }
    bf16x4 p[4];
#pragma unroll
    for (int t = 0; t < 4; ++t)
#pragma unroll
      for (int r = 0; r < 4; ++r) p[t][r] = (bf16)sv[t * 4 + r];
    *(bf16x4*)&P_lds[0][fr][fg * 4]      = p[0];
    *(bf16x4*)&P_lds[0][fr][16 + fg * 4] = p[1];
    *(bf16x4*)&P_lds[1][fr][fg * 4]      = p[2];
    *(bf16x4*)&P_lds[1][fr][16 + fg * 4] = p[3];
    const bf16x8 pf0 = *(const bf16x8*)&P_lds[0][fr][fg * 8];
    const bf16x8 pf1 = *(const bf16x8*)&P_lds[1][fr][fg * 8];
#pragma unroll
    for (int c = 0; c < 4; ++c)
      Oacc[c] = __builtin_amdgcn_mfma_f32_16x16x32_bf16(pf0, vf[0][c], Oacc[c], 0, 0, 0);
#pragma unroll
    for (int c = 0; c < 4; ++c)
      Oacc[c] = __builtin_amdgcn_mfma_f32_16x16x32_bf16(pf1, vf[1][c], Oacc[c], 0, 0, 0);
  }
  // ---- remainder: 32 kv per iteration ----
  for (; kv0 < kv_end; kv0 += 32) {
    float sv[8];
    float mx = -1e30f;
    bf16x8 vf[4];
#pragma unroll
    for (int c = 0; c < 4; ++c)
      vf[c] = *(const bf16x8*)(VT + (size_t)(b * 64 + c * 16 + fr) * NN + kv0 + fg * 8);
#pragma unroll
    for (int t = 0; t < 2; ++t) {
      const size_t koff = (size_t)(b * NN + kv0 + t * 16 + fr) * 128 + fg * 8;
      bf16x8 kf0 = *(const bf16x8*)(KV + koff);
      bf16x8 kf1 = *(const bf16x8*)(KV + koff + 32);
      f32x4 z = {0.f, 0.f, 0.f, 0.f};
      z = __builtin_amdgcn_mfma_f32_16x16x32_bf16(kf0, qf0, z, 0, 0, 0);
      z = __builtin_amdgcn_mfma_f32_16x16x32_bf16(kf1, qf1, z, 0, 0, 0);
#pragma unroll
      for (int r = 0; r < 4; ++r) {
        const int kv = kv0 + t * 16 + fg * 4 + r;
        const int d = (q0 + fr) - kv;
        const int dc = d > 0 ? d : 0;
        float val = z[r] + bt[dc];
        if (d < 0) val = -1e30f;
        sv[t * 4 + r] = val;
        mx = fmaxf(mx, val);
      }
    }
    mx = fmaxf(mx, __shfl_xor(mx, 16));
    mx = fmaxf(mx, __shfl_xor(mx, 32));
    const float m_new = fmaxf(m_run, mx);
    const float sc_old = __expf(m_run - m_new);
    float csum = 0.0f;
#pragma unroll
    for (int i = 0; i < 8; ++i) { sv[i] = __expf(sv[i] - m_new); csum += sv[i]; }
    csum += __shfl_xor(csum, 16);
    csum += __shfl_xor(csum, 32);
    l_run = l_run * sc_old + csum;
    m_run = m_new;
#pragma unroll
    for (int r = 0; r < 4; ++r) {
      const float f = __shfl(sc_old, fg * 4 + r);
#pragma unroll
      for (int c = 0; c < 4; ++c) Oacc[c][r] *= f;
    }
    bf16x4 p0, p1;
#pragma unroll
    for (int r = 0; r < 4; ++r) { p0[r] = (bf16)sv[r]; p1[r] = (bf16)sv[4 + r]; }
    *(bf16x4*)&P_lds[0][fr][fg * 4] = p0;
    *(bf16x4*)&P_lds[0][fr][16 + fg * 4] = p1;
    const bf16x8 pf = *(const bf16x8*)&P_lds[0][fr][fg * 8];
#pragma unroll
    for (int c = 0; c < 4; ++c)
      Oacc[c] = __builtin_amdgcn_mfma_f32_16x16x32_bf16(pf, vf[c], Oacc[c], 0, 0, 0);
  }
  const float linv = 1.0f / l_run;
#pragma unroll
  for (int r = 0; r < 4; ++r) {
    const float f = __shfl(linv, fg * 4 + r);
    const size_t orow = (size_t)(b * NN + q0 + fg * 4 + r) * INNER + h * DH;
#pragma unroll
    for (int c = 0; c < 4; ++c) O[orow + c * 16 + fr] = (bf16)(Oacc[c][r] * f);
  }
}

// ======================= GEGLU elementwise (in-place into hg) ===================
__global__ void gelu_mul_kernel(const bf16* __restrict__ ha, bf16* __restrict__ hg) {
  const size_t total = (size_t)MROW * FFP / 8;
  for (size_t i = (size_t)blockIdx.x * blockDim.x + threadIdx.x; i < total;
       i += (size_t)gridDim.x * blockDim.x) {
    bf16x8 a = *(const bf16x8*)(ha + i * 8);
    bf16x8 g = *(const bf16x8*)(hg + i * 8);
    bf16x8 r;
#pragma unroll
    for (int j = 0; j < 8; ++j) {
      float gv = (float)g[j], av = (float)a[j];
      float ge = 0.5f * gv * (1.0f + erff(gv * 0.70710678118654752f));
      r[j] = (bf16)(ge * av);
    }
    *(bf16x8*)(hg + i * 8) = r;
  }
}

// ======================= launch ==========================
extern "C" void kernel_launch(void* const* d_in, const int* in_sizes, int n_in,
                              void* d_out, int out_size, void* d_ws, size_t ws_size,
                              hipStream_t stream) {
  (void)in_sizes; (void)n_in; (void)out_size;
  const float* in_x  = (const float*)d_in[0];
  const float* rel   = (const float*)d_in[1];
  const float* ln1g  = (const float*)d_in[2];
  const float* ln1b  = (const float*)d_in[3];
  const float* wq    = (const float*)d_in[4];
  const float* wkv   = (const float*)d_in[5];
  const float* wo    = (const float*)d_in[6];
  const float* ln2g  = (const float*)d_in[7];
  const float* ln2b  = (const float*)d_in[8];
  const float* w1    = (const float*)d_in[9];
  const float* w2    = (const float*)d_in[10];
  const float* lnfg  = (const float*)d_in[11];
  const float* lnfb  = (const float*)d_in[12];
  float* out = (float*)d_out;

  constexpr size_t E_WQ  = (size_t)INNER * DIM;
  constexpr size_t E_WKV = (size_t)128 * DIM;
  constexpr size_t E_WO  = (size_t)DIM * INNER;
  constexpr size_t E_W1  = (size_t)FFP * DIM;
  constexpr size_t E_W2  = (size_t)DIM * FFP;
  bf16* wqT  = (bf16*)d_ws;
  bf16* wkvT = wqT  + NLAY * E_WQ;
  bf16* woT  = wkvT + NLAY * E_WKV;
  bf16* w1aT = woT  + NLAY * E_WO;
  bf16* w1gT = w1aT + NLAY * E_W1;
  bf16* w2T  = w1gT + NLAY * E_W1;
  bf16* xnb  = w2T  + NLAY * E_W2;
  bf16* qb   = xnb  + (size_t)MROW * DIM;
  bf16* kvb  = qb   + (size_t)MROW * INNER;
  bf16* vTb  = kvb  + (size_t)MROW * 128;
  bf16* ob   = vTb  + (size_t)NB * 64 * NN;
  bf16* hab  = ob   + (size_t)MROW * INNER;
  bf16* hgb  = hab  + (size_t)MROW * FFP;
  float* xbuf = (float*)(hgb + (size_t)MROW * FFP);
  float* btab = xbuf + (size_t)MROW * DIM;
  const size_t needed = (size_t)((char*)(btab + NH * NN) - (char*)d_ws);
  if (ws_size < needed) return;  // visible clean failure instead of corruption

  hipMemcpyAsync(xbuf, in_x, (size_t)MROW * DIM * sizeof(float),
                 hipMemcpyDeviceToDevice, stream);
  btab_kernel<<<8, 256, 0, stream>>>(rel, btab);

  const dim3 tb(32, 8);
  conv_tr<<<dim3(16, 32, 6), tb, 0, stream>>>(wq,  (size_t)DIM*INNER, INNER, 0, DIM, INNER,
                                              wqT,  E_WQ, DIM, 0.125f);   // fold DH^-0.5
  conv_tr<<<dim3(4, 32, 6),  tb, 0, stream>>>(wkv, (size_t)DIM*128, 128, 0, DIM, 128,
                                              wkvT, E_WKV, DIM, 1.0f);
  conv_tr<<<dim3(32, 16, 6), tb, 0, stream>>>(wo,  (size_t)INNER*DIM, DIM, 0, INNER, DIM,
                                              woT,  E_WO, INNER, 1.0f);
  conv_tr<<<dim3(88, 32, 6), tb, 0, stream>>>(w1,  (size_t)DIM*2*FF, 2*FF, 0, DIM, FF,
                                              w1aT, E_W1, DIM, 1.0f);
  conv_tr<<<dim3(88, 32, 6), tb, 0, stream>>>(w1,  (size_t)DIM*2*FF, 2*FF, FF, DIM, FF,
                                              w1gT, E_W1, DIM, 1.0f);
  conv_tr<<<dim3(32, 88, 6), tb, 0, stream>>>(w2,  (size_t)FF*DIM, DIM, 0, FF, DIM,
                                              w2T,  E_W2, FFP, 1.0f);

  for (int l = 0; l < NLAY; ++l) {
    ln_kernel<bf16><<<MROW, 256, 0, stream>>>(xbuf, ln1g + l*DIM, ln1b + l*DIM, xnb);
    gemm_bt<0><<<dim3(INNER/128, MROW/128), 256, 0, stream>>>(xnb, wqT + l*E_WQ, DIM, INNER, qb, nullptr);
    gemm_bt<0><<<dim3(1, MROW/128), 256, 0, stream>>>(xnb, wkvT + l*E_WKV, DIM, 128, kvb, nullptr);
    vt_kernel<<<dim3(NN/32, 2, NB), tb, 0, stream>>>(kvb, vTb);
    attn_kernel<<<dim3(NN/16, NH, NB), 64, 0, stream>>>(qb, kvb, vTb, btab, ob);
    gemm_bt<1><<<dim3(DIM/128, MROW/128), 256, 0, stream>>>(ob, woT + l*E_WO, INNER, DIM, nullptr, xbuf);
    ln_kernel<bf16><<<MROW, 256, 0, stream>>>(xbuf, ln2g + l*DIM, ln2b + l*DIM, xnb);
    gemm_bt<0><<<dim3(FFP/128, MROW/128), 256, 0, stream>>>(xnb, w1aT + l*E_W1, DIM, FFP, hab, nullptr);
    gemm_bt<0><<<dim3(FFP/128, MROW/128), 256, 0, stream>>>(xnb, w1gT + l*E_W1, DIM, FFP, hgb, nullptr);
    gelu_mul_kernel<<<2048, 256, 0, stream>>>(hab, hgb);
    gemm_bt<1><<<dim3(DIM/128, MROW/128), 256, 0, stream>>>(hgb, w2T + l*E_W2, FFP, DIM, nullptr, xbuf);
  }
  ln_kernel<float><<<MROW, 256, 0, stream>>>(xbuf, lnfg, lnfb, out);
}

// Round 3
// 2118.468 us; speedup vs baseline: 1.2367x; 1.2367x over previous
//
#include <hip/hip_runtime.h>
#include <cstdint>
#include <cstddef>

using bf16 = __bf16;
typedef __bf16 bf16x8 __attribute__((ext_vector_type(8)));
typedef __bf16 bf16x4 __attribute__((ext_vector_type(4)));
typedef float  f32x4  __attribute__((ext_vector_type(4)));

// ---- problem constants ----
constexpr int NB   = 2;      // batch
constexpr int NN   = 2048;   // seq
constexpr int DIM  = 1024;
constexpr int NH   = 8;
constexpr int DH   = 64;
constexpr int INNER= 512;
constexpr int QKVN = 640;    // fused Q(512) + K(64) + V(64) projection width
constexpr int FF   = 2730;
constexpr int FFP  = 2816;   // padded FF (22*128)
constexpr int MROW = NB * NN;   // 4096
constexpr int NLAY = 6;
constexpr int AROWS = NB * NH * NN;  // 32768 attention (b,h,q) rows

// async global->LDS, 16B per lane; LDS dest is wave-uniform base (+lane*16 by HW)
__device__ __forceinline__ void gload_lds16(const bf16* g, bf16* l) {
  __builtin_amdgcn_global_load_lds((const __attribute__((address_space(1))) void*)g,
                                   (__attribute__((address_space(3))) void*)l,
                                   16, 0, 0);
}

// ======================= bias table ==========================
__global__ void btab_kernel(const float* __restrict__ rel, float* __restrict__ btab) {
  int d = blockIdx.x * 256 + threadIdx.x;
  if (d >= NN) return;
  int bucket;
  if (d < 16) bucket = d;
  else {
    int vl = 16 + (int)(logf((float)d / 16.0f) / logf(8.0f) * 16.0f);
    bucket = vl < 31 ? vl : 31;
  }
  for (int h = 0; h < NH; ++h) btab[h * NN + d] = rel[bucket * NH + h];
}

// ============== weight convert + transpose (+pad, +scale) ==============
__global__ void conv_tr(const float* __restrict__ src, size_t srcLayer, int srcStride,
                        int colOff, int R, int C,
                        bf16* __restrict__ dst, size_t dstLayer, int Tcols, float scale) {
  __shared__ float tile[32][33];
  const int i0 = blockIdx.x * 32, j0 = blockIdx.y * 32, z = blockIdx.z;
  const float* s = src + (size_t)z * srcLayer;
  bf16* d = dst + (size_t)z * dstLayer;
  const int tx = threadIdx.x, ty = threadIdx.y;
#pragma unroll
  for (int k = 0; k < 4; ++k) {
    int j = j0 + ty + k * 8;
    int i = i0 + tx;
    float v = 0.0f;
    if (j < R && i < C) v = s[(size_t)j * srcStride + colOff + i] * scale;
    tile[ty + k * 8][tx] = v;
  }
  __syncthreads();
#pragma unroll
  for (int k = 0; k < 4; ++k) {
    int i = i0 + ty + k * 8;   // dst row
    int j = j0 + tx;           // dst col
    d[(size_t)i * Tcols + j] = (bf16)tile[tx][ty + k * 8];
  }
}

// ======================= LayerNorm ==========================
template <typename OUT>
__global__ void ln_kernel(const float* __restrict__ X, const float* __restrict__ G,
                          const float* __restrict__ Bt, OUT* __restrict__ out) {
  __shared__ float red[8];
  const int row = blockIdx.x, t = threadIdx.x;
  const float* xr = X + (size_t)row * DIM;
  float4 v = *(const float4*)(xr + t * 4);
  float s  = v.x + v.y + v.z + v.w;
  float s2 = v.x * v.x + v.y * v.y + v.z * v.z + v.w * v.w;
#pragma unroll
  for (int o = 1; o < 64; o <<= 1) { s += __shfl_xor(s, o); s2 += __shfl_xor(s2, o); }
  if ((t & 63) == 0) { red[t >> 6] = s; red[4 + (t >> 6)] = s2; }
  __syncthreads();
  float S  = red[0] + red[1] + red[2] + red[3];
  float S2 = red[4] + red[5] + red[6] + red[7];
  const float inv = 1.0f / (float)DIM;
  float mu = S * inv;
  float var = S2 * inv - mu * mu;
  float rstd = rsqrtf(var + 1e-5f);
  float4 g  = *(const float4*)(G + t * 4);
  float4 bb = *(const float4*)(Bt + t * 4);
  OUT* orow = out + (size_t)row * DIM + t * 4;
  orow[0] = (OUT)((v.x - mu) * rstd * g.x + bb.x);
  orow[1] = (OUT)((v.y - mu) * rstd * g.y + bb.y);
  orow[2] = (OUT)((v.z - mu) * rstd * g.z + bb.z);
  orow[3] = (OUT)((v.w - mu) * rstd * g.w + bb.w);
}

// ======================= GEMM: C[M,N] = A[M,K] @ B^T[N,K] ==========================
// 128x128 tile, BK=64, 4 waves. Pipelined 2-phase: double-buffered LDS, next-tile
// global_load_lds issued BEFORE computing current (DMA hides under MFMA), raw
// s_barrier + explicit vmcnt so __syncthreads' vmcnt(0) drain doesn't kill the
// pipeline. LDS bank-conflict fix per m173/rule#21: pre-swizzled GLOBAL source col
// + linear LDS dest + XOR on read. XCD-aware block swizzle (nwg%8==0 for all grids).
template <int MODE>  // 0: store bf16 C;  1: Xr += acc (fp32 residual)
__launch_bounds__(256)
__global__ void gemm_bt(const bf16* __restrict__ A, const bf16* __restrict__ B,
                        int K, int N, bf16* __restrict__ Cb, float* __restrict__ Xr) {
  __shared__ __align__(16) bf16 As[2][128 * 64];
  __shared__ __align__(16) bf16 Bs[2][128 * 64];
  const int tid = threadIdx.x;
  const int lane = tid & 63, wave = tid >> 6;
  const int gx = gridDim.x, gy = gridDim.y;
  const int nwg = gx * gy;
  const int orig = blockIdx.y * gx + blockIdx.x;
  const int wgid = (orig & 7) * (nwg >> 3) + (orig >> 3);  // XCD swizzle (nwg%8==0)
  const int m0 = (wgid % gy) * 128;   // M fastest within XCD chunk -> B-panel L2 reuse
  const int n0 = (wgid / gy) * 128;
  const int wm = (wave >> 1) * 64, wn = (wave & 1) * 64;
  const int fr = lane & 15, fg8 = (lane >> 4) * 8;
  const int frl8 = (fr & 7) * 8;           // read-side swizzle XOR
  const int rL = lane >> 3;                // staging row within 8-row group
  const int cS = ((lane & 7) ^ rL) * 8;    // pre-swizzled global source col
  const bf16* aB = A + (size_t)(m0 + wave * 8 + rL) * K + cS;
  const bf16* bB = B + (size_t)(n0 + wave * 8 + rL) * K + cS;
  f32x4 acc[4][4] = {};

  auto STAGE = [&](int buf, int kt) {
#pragma unroll
    for (int r = 0; r < 4; ++r) {
      gload_lds16(aB + (size_t)(r * 32) * K + kt, &As[buf][(r * 4 + wave) * 512]);
      gload_lds16(bB + (size_t)(r * 32) * K + kt, &Bs[buf][(r * 4 + wave) * 512]);
    }
  };

  STAGE(0, 0);
  const int nt = K >> 6;
  int cur = 0;
  for (int t = 0; t < nt; ++t) {
    asm volatile("s_waitcnt vmcnt(0)" ::: "memory");  // buf[cur] DMA (this wave) done
    __builtin_amdgcn_s_barrier();                     // all waves' portions done
    __builtin_amdgcn_sched_barrier(0);
    if (t + 1 < nt) STAGE(cur ^ 1, (t + 1) * 64);     // in flight across the compute
#pragma unroll
    for (int kk = 0; kk < 64; kk += 32) {
      bf16x8 af[4], bfr[4];
#pragma unroll
      for (int m = 0; m < 4; ++m)
        af[m] = *(const bf16x8*)&As[cur][(wm + m * 16 + fr) * 64 + ((kk + fg8) ^ frl8)];
#pragma unroll
      for (int n = 0; n < 4; ++n)
        bfr[n] = *(const bf16x8*)&Bs[cur][(wn + n * 16 + fr) * 64 + ((kk + fg8) ^ frl8)];
#pragma unroll
      for (int m = 0; m < 4; ++m)
#pragma unroll
        for (int n = 0; n < 4; ++n)
          acc[m][n] = __builtin_amdgcn_mfma_f32_16x16x32_bf16(af[m], bfr[n], acc[m][n], 0, 0, 0);
    }
    __builtin_amdgcn_sched_barrier(0);
    __builtin_amdgcn_s_barrier();                     // cur fully read; next STAGE may overwrite
    cur ^= 1;
  }
  const int cc = lane & 15, cg = (lane >> 4) * 4;
#pragma unroll
  for (int m = 0; m < 4; ++m) {
#pragma unroll
    for (int n = 0; n < 4; ++n) {
      const int col = n0 + wn + n * 16 + cc;
#pragma unroll
      for (int r = 0; r < 4; ++r) {
        const int row = m0 + wm + m * 16 + cg + r;
        const size_t idx = (size_t)row * N + col;
        if (MODE == 0) Cb[idx] = (bf16)acc[m][n][r];
        else           Xr[idx] += acc[m][n][r];
      }
    }
  }
}

// ======================= V transpose: VT[b][dh][n] = QKV[b*NN+n][576+dh] ==========
__global__ void vt_kernel(const bf16* __restrict__ QKV, bf16* __restrict__ VT) {
  __shared__ bf16 t[32][33];
  const int n0 = blockIdx.x * 32, d0 = blockIdx.y * 32, b = blockIdx.z;
  const int tx = threadIdx.x, ty = threadIdx.y;
#pragma unroll
  for (int k = 0; k < 4; ++k) {
    int n = n0 + ty + k * 8;
    t[ty + k * 8][tx] = QKV[(size_t)(b * NN + n) * QKVN + 576 + d0 + tx];
  }
  __syncthreads();
#pragma unroll
  for (int k = 0; k < 4; ++k) {
    int dh = d0 + ty + k * 8;
    VT[(size_t)(b * 64 + dh) * NN + n0 + tx] = t[tx][ty + k * 8];
  }
}

// ======================= attention (split-KV partials) ==========================
// 1 wave/block, 16 q rows, one kv-split per block. Swapped QK^T: lane holds
// S[q=lane&15][kv=(lane>>4)*4+r]. Online softmax fp32 with defer-max (T13).
// Writes UNNORMALIZED O partial + (m,l) to workspace; combine kernel merges.
__launch_bounds__(64)
__global__ void attn_kernel(const bf16* __restrict__ QKV, const bf16* __restrict__ VT,
                            const float* __restrict__ btab,
                            float* __restrict__ Opart, float* __restrict__ mlbuf) {
  __shared__ bf16 P_lds[2][16][40];
  const int lane = threadIdx.x;
  const int split = blockIdx.x & 1;
  const int qt = (NN / 16 - 1) - (blockIdx.x >> 1);   // longest-first
  const int h = blockIdx.y, b = blockIdx.z;
  const int q0 = qt * 16;
  const int fr = lane & 15, fg = lane >> 4;
  const int Rbase = (b * NH + h) * NN + q0;
  const int kv_full = q0 + 16;
  const int half = (kv_full >= 64) ? ((kv_full / 2) & ~31) : 0;
  const int lo = split ? half : 0;
  const int hi = split ? kv_full : half;
  if (hi <= lo) {              // empty split: weight 0 in combine
    if (fg == 0) {
      float2* ml = (float2*)&mlbuf[(size_t)(split * AROWS + Rbase + fr) * 2];
      *ml = make_float2(-1e30f, 0.0f);
    }
    return;
  }
  const float* bt = btab + h * NN;
  bf16x8 qf0, qf1;
  {
    const size_t qoff = (size_t)(b * NN + q0 + fr) * QKVN + h * DH + fg * 8;
    qf0 = *(const bf16x8*)(QKV + qoff);
    qf1 = *(const bf16x8*)(QKV + qoff + 32);
  }
  f32x4 Oacc[4] = {};
  float m_run = -1e30f, l_run = 0.0f;
  int kv0 = lo;
  // ---- main: 64 kv / iter ----
  for (; kv0 + 64 <= hi; kv0 += 64) {
    bf16x8 kf[4][2];
#pragma unroll
    for (int t = 0; t < 4; ++t) {
      const size_t koff = (size_t)(b * NN + kv0 + t * 16 + fr) * QKVN + 512 + fg * 8;
      kf[t][0] = *(const bf16x8*)(QKV + koff);
      kf[t][1] = *(const bf16x8*)(QKV + koff + 32);
    }
    bf16x8 vf[2][4];
#pragma unroll
    for (int ch = 0; ch < 2; ++ch)
#pragma unroll
      for (int c = 0; c < 4; ++c)
        vf[ch][c] = *(const bf16x8*)(VT + (size_t)(b * 64 + c * 16 + fr) * NN + kv0 + ch * 32 + fg * 8);
    f32x4 z[4];
#pragma unroll
    for (int t = 0; t < 4; ++t) {
      f32x4 zz = {0.f, 0.f, 0.f, 0.f};
      zz = __builtin_amdgcn_mfma_f32_16x16x32_bf16(kf[t][0], qf0, zz, 0, 0, 0);
      zz = __builtin_amdgcn_mfma_f32_16x16x32_bf16(kf[t][1], qf1, zz, 0, 0, 0);
      z[t] = zz;
    }
    float sv[16];
    float mx = -1e30f;
#pragma unroll
    for (int t = 0; t < 4; ++t)
#pragma unroll
      for (int r = 0; r < 4; ++r) {
        const int kv = kv0 + t * 16 + fg * 4 + r;
        const int d = (q0 + fr) - kv;
        const int dc = d > 0 ? d : 0;
        float val = z[t][r] + bt[dc];
        if (d < 0) val = -1e30f;
        sv[t * 4 + r] = val;
        mx = fmaxf(mx, val);
      }
    mx = fmaxf(mx, __shfl_xor(mx, 16));
    mx = fmaxf(mx, __shfl_xor(mx, 32));
    if (!__all(mx <= m_run + 8.0f)) {     // defer-max: rescale only on real growth
      const float m_new = fmaxf(m_run, mx);
      const float sc_old = __expf(m_run - m_new);
      l_run *= sc_old;
#pragma unroll
      for (int r = 0; r < 4; ++r) {
        const float f = __shfl(sc_old, fg * 4 + r);
#pragma unroll
        for (int c = 0; c < 4; ++c) Oacc[c][r] *= f;
      }
      m_run = m_new;
    }
    float csum = 0.0f;
#pragma unroll
    for (int i = 0; i < 16; ++i) { sv[i] = __expf(sv[i] - m_run); csum += sv[i]; }
    csum += __shfl_xor(csum, 16);
    csum += __shfl_xor(csum, 32);
    l_run += csum;
    bf16x4 p[4];
#pragma unroll
    for (int t = 0; t < 4; ++t)
#pragma unroll
      for (int r = 0; r < 4; ++r) p[t][r] = (bf16)sv[t * 4 + r];
    *(bf16x4*)&P_lds[0][fr][fg * 4]      = p[0];
    *(bf16x4*)&P_lds[0][fr][16 + fg * 4] = p[1];
    *(bf16x4*)&P_lds[1][fr][fg * 4]      = p[2];
    *(bf16x4*)&P_lds[1][fr][16 + fg * 4] = p[3];
    const bf16x8 pf0 = *(const bf16x8*)&P_lds[0][fr][fg * 8];
    const bf16x8 pf1 = *(const bf16x8*)&P_lds[1][fr][fg * 8];
#pragma unroll
    for (int c = 0; c < 4; ++c)
      Oacc[c] = __builtin_amdgcn_mfma_f32_16x16x32_bf16(pf0, vf[0][c], Oacc[c], 0, 0, 0);
#pragma unroll
    for (int c = 0; c < 4; ++c)
      Oacc[c] = __builtin_amdgcn_mfma_f32_16x16x32_bf16(pf1, vf[1][c], Oacc[c], 0, 0, 0);
  }
  // ---- remainder: 32 kv / iter (may overshoot into causal-masked region) ----
  for (; kv0 < hi; kv0 += 32) {
    float sv[8];
    float mx = -1e30f;
    bf16x8 vf[4];
#pragma unroll
    for (int c = 0; c < 4; ++c)
      vf[c] = *(const bf16x8*)(VT + (size_t)(b * 64 + c * 16 + fr) * NN + kv0 + fg * 8);
#pragma unroll
    for (int t = 0; t < 2; ++t) {
      const size_t koff = (size_t)(b * NN + kv0 + t * 16 + fr) * QKVN + 512 + fg * 8;
      bf16x8 kf0 = *(const bf16x8*)(QKV + koff);
      bf16x8 kf1 = *(const bf16x8*)(QKV + koff + 32);
      f32x4 z = {0.f, 0.f, 0.f, 0.f};
      z = __builtin_amdgcn_mfma_f32_16x16x32_bf16(kf0, qf0, z, 0, 0, 0);
      z = __builtin_amdgcn_mfma_f32_16x16x32_bf16(kf1, qf1, z, 0, 0, 0);
#pragma unroll
      for (int r = 0; r < 4; ++r) {
        const int kv = kv0 + t * 16 + fg * 4 + r;
        const int d = (q0 + fr) - kv;
        const int dc = d > 0 ? d : 0;
        float val = z[r] + bt[dc];
        if (d < 0) val = -1e30f;
        sv[t * 4 + r] = val;
        mx = fmaxf(mx, val);
      }
    }
    mx = fmaxf(mx, __shfl_xor(mx, 16));
    mx = fmaxf(mx, __shfl_xor(mx, 32));
    if (!__all(mx <= m_run + 8.0f)) {
      const float m_new = fmaxf(m_run, mx);
      const float sc_old = __expf(m_run - m_new);
      l_run *= sc_old;
#pragma unroll
      for (int r = 0; r < 4; ++r) {
        const float f = __shfl(sc_old, fg * 4 + r);
#pragma unroll
        for (int c = 0; c < 4; ++c) Oacc[c][r] *= f;
      }
      m_run = m_new;
    }
    float csum = 0.0f;
#pragma unroll
    for (int i = 0; i < 8; ++i) { sv[i] = __expf(sv[i] - m_run); csum += sv[i]; }
    csum += __shfl_xor(csum, 16);
    csum += __shfl_xor(csum, 32);
    l_run += csum;
    bf16x4 p0, p1;
#pragma unroll
    for (int r = 0; r < 4; ++r) { p0[r] = (bf16)sv[r]; p1[r] = (bf16)sv[4 + r]; }
    *(bf16x4*)&P_lds[0][fr][fg * 4] = p0;
    *(bf16x4*)&P_lds[0][fr][16 + fg * 4] = p1;
    const bf16x8 pf = *(const bf16x8*)&P_lds[0][fr][fg * 8];
#pragma unroll
    for (int c = 0; c < 4; ++c)
      Oacc[c] = __builtin_amdgcn_mfma_f32_16x16x32_bf16(pf, vf[c], Oacc[c], 0, 0, 0);
  }
  // ---- write unnormalized partial ----
  const size_t pb = (size_t)split * AROWS + Rbase;
#pragma unroll
  for (int r = 0; r < 4; ++r) {
    float* prow = Opart + (pb + fg * 4 + r) * 64;
#pragma unroll
    for (int c = 0; c < 4; ++c) prow[c * 16 + fr] = Oacc[c][r];
  }
  if (fg == 0) {
    float2* ml = (float2*)&mlbuf[(pb + fr) * 2];
    *ml = make_float2(m_run, l_run);
  }
}

// ======================= combine split-KV partials -> O (bf16) =================
__global__ void attn_combine(const float* __restrict__ Opart, const float* __restrict__ mlbuf,
                             bf16* __restrict__ O) {
  const int gtid = blockIdx.x * 256 + threadIdx.x;   // AROWS*16 threads
  const int R = gtid >> 4;
  const int dc = (gtid & 15) * 4;
  const float2 ml0 = ((const float2*)mlbuf)[R];
  const float2 ml1 = ((const float2*)mlbuf)[AROWS + R];
  const float m = fmaxf(ml0.x, ml1.x);
  const float w0 = __expf(ml0.x - m), w1 = __expf(ml1.x - m);
  const float inv = 1.0f / (ml0.y * w0 + ml1.y * w1);
  const f32x4 o0 = *(const f32x4*)(Opart + (size_t)R * 64 + dc);
  const f32x4 o1 = *(const f32x4*)(Opart + ((size_t)AROWS + R) * 64 + dc);
  const int q = R & (NN - 1);
  const int h = (R >> 11) & (NH - 1);
  const int b = R >> 14;
  bf16* orow = O + (size_t)(b * NN + q) * INNER + h * DH + dc;
  bf16x4 res;
#pragma unroll
  for (int j = 0; j < 4; ++j) res[j] = (bf16)((o0[j] * w0 + o1[j] * w1) * inv);
  *(bf16x4*)orow = res;
}

// ======================= GEGLU elementwise (in-place into hg) ===================
__global__ void gelu_mul_kernel(const bf16* __restrict__ ha, bf16* __restrict__ hg) {
  const size_t total = (size_t)MROW * FFP / 8;
  for (size_t i = (size_t)blockIdx.x * blockDim.x + threadIdx.x; i < total;
       i += (size_t)gridDim.x * blockDim.x) {
    bf16x8 a = *(const bf16x8*)(ha + i * 8);
    bf16x8 g = *(const bf16x8*)(hg + i * 8);
    bf16x8 r;
#pragma unroll
    for (int j = 0; j < 8; ++j) {
      float gv = (float)g[j], av = (float)a[j];
      float ge = 0.5f * gv * (1.0f + erff(gv * 0.70710678118654752f));
      r[j] = (bf16)(ge * av);
    }
    *(bf16x8*)(hg + i * 8) = r;
  }
}

// ======================= launch ==========================
extern "C" void kernel_launch(void* const* d_in, const int* in_sizes, int n_in,
                              void* d_out, int out_size, void* d_ws, size_t ws_size,
                              hipStream_t stream) {
  (void)in_sizes; (void)n_in; (void)out_size;
  const float* in_x  = (const float*)d_in[0];
  const float* rel   = (const float*)d_in[1];
  const float* ln1g  = (const float*)d_in[2];
  const float* ln1b  = (const float*)d_in[3];
  const float* wq    = (const float*)d_in[4];
  const float* wkv   = (const float*)d_in[5];
  const float* wo    = (const float*)d_in[6];
  const float* ln2g  = (const float*)d_in[7];
  const float* ln2b  = (const float*)d_in[8];
  const float* w1    = (const float*)d_in[9];
  const float* w2    = (const float*)d_in[10];
  const float* lnfg  = (const float*)d_in[11];
  const float* lnfb  = (const float*)d_in[12];
  float* out = (float*)d_out;

  constexpr size_t E_QKV = (size_t)QKVN * DIM;   // fused wq|wkv, [640][1024]
  constexpr size_t E_WO  = (size_t)DIM * INNER;
  constexpr size_t E_W1  = (size_t)FFP * DIM;
  constexpr size_t E_W2  = (size_t)DIM * FFP;
  bf16* wqkvT = (bf16*)d_ws;
  bf16* woT  = wqkvT + NLAY * E_QKV;
  bf16* w1aT = woT  + NLAY * E_WO;
  bf16* w1gT = w1aT + NLAY * E_W1;
  bf16* w2T  = w1gT + NLAY * E_W1;
  bf16* xnb  = w2T  + NLAY * E_W2;
  bf16* qkvb = xnb  + (size_t)MROW * DIM;
  bf16* vTb  = qkvb + (size_t)MROW * QKVN;
  bf16* ob   = vTb  + (size_t)NB * 64 * NN;
  bf16* hab  = ob   + (size_t)MROW * INNER;
  bf16* hgb  = hab  + (size_t)MROW * FFP;
  float* xbuf = (float*)(hgb + (size_t)MROW * FFP);
  float* btab = xbuf + (size_t)MROW * DIM;
  const size_t needed = (size_t)((char*)(btab + NH * NN) - (char*)d_ws);
  if (ws_size < needed) return;  // visible clean failure instead of corruption
  // attn partials overlaid on FF buffers (idle during attention)
  float* Opart = (float*)(((uintptr_t)hab + 15) & ~(uintptr_t)15);  // 2*AROWS*64 f32 = 16.8MB <= 23MB
  float* mlbuf = (float*)(((uintptr_t)hgb + 15) & ~(uintptr_t)15);  // 2*AROWS*2 f32 = 512KB

  hipMemcpyAsync(xbuf, in_x, (size_t)MROW * DIM * sizeof(float),
                 hipMemcpyDeviceToDevice, stream);
  btab_kernel<<<8, 256, 0, stream>>>(rel, btab);

  const dim3 tb(32, 8);
  conv_tr<<<dim3(16, 32, 6), tb, 0, stream>>>(wq,  (size_t)DIM*INNER, INNER, 0, DIM, INNER,
                                              wqkvT, E_QKV, DIM, 0.125f);  // fold DH^-0.5
  conv_tr<<<dim3(4, 32, 6),  tb, 0, stream>>>(wkv, (size_t)DIM*128, 128, 0, DIM, 128,
                                              wqkvT + (size_t)INNER*DIM, E_QKV, DIM, 1.0f);
  conv_tr<<<dim3(32, 16, 6), tb, 0, stream>>>(wo,  (size_t)INNER*DIM, DIM, 0, INNER, DIM,
                                              woT,  E_WO, INNER, 1.0f);
  conv_tr<<<dim3(88, 32, 6), tb, 0, stream>>>(w1,  (size_t)DIM*2*FF, 2*FF, 0, DIM, FF,
                                              w1aT, E_W1, DIM, 1.0f);
  conv_tr<<<dim3(88, 32, 6), tb, 0, stream>>>(w1,  (size_t)DIM*2*FF, 2*FF, FF, DIM, FF,
                                              w1gT, E_W1, DIM, 1.0f);
  conv_tr<<<dim3(32, 88, 6), tb, 0, stream>>>(w2,  (size_t)FF*DIM, DIM, 0, FF, DIM,
                                              w2T,  E_W2, FFP, 1.0f);

  for (int l = 0; l < NLAY; ++l) {
    ln_kernel<bf16><<<MROW, 256, 0, stream>>>(xbuf, ln1g + l*DIM, ln1b + l*DIM, xnb);
    gemm_bt<0><<<dim3(QKVN/128, MROW/128), 256, 0, stream>>>(xnb, wqkvT + l*E_QKV, DIM, QKVN, qkvb, nullptr);
    vt_kernel<<<dim3(NN/32, 2, NB), tb, 0, stream>>>(qkvb, vTb);
    attn_kernel<<<dim3((NN/16)*2, NH, NB), 64, 0, stream>>>(qkvb, vTb, btab, Opart, mlbuf);
    attn_combine<<<AROWS*16/256, 256, 0, stream>>>(Opart, mlbuf, ob);
    gemm_bt<1><<<dim3(DIM/128, MROW/128), 256, 0, stream>>>(ob, woT + l*E_WO, INNER, DIM, nullptr, xbuf);
    ln_kernel<bf16><<<MROW, 256, 0, stream>>>(xbuf, ln2g + l*DIM, ln2b + l*DIM, xnb);
    gemm_bt<0><<<dim3(FFP/128, MROW/128), 256, 0, stream>>>(xnb, w1aT + l*E_W1, DIM, FFP, hab, nullptr);
    gemm_bt<0><<<dim3(FFP/128, MROW/128), 256, 0, stream>>>(xnb, w1gT + l*E_W1, DIM, FFP, hgb, nullptr);
    gelu_mul_kernel<<<2048, 256, 0, stream>>>(hab, hgb);
    gemm_bt<1><<<dim3(DIM/128, MROW/128), 256, 0, stream>>>(hgb, w2T + l*E_W2, FFP, DIM, nullptr, xbuf);
  }
  ln_kernel<float><<<MROW, 256, 0, stream>>>(xbuf, lnfg, lnfb, out);
}